// Round 3
// baseline (1719.669 us; speedup 1.0000x reference)
//
#include <hip/hip_runtime.h>
#include <type_traits>

namespace {

constexpr int KK   = 7;
constexpr int PADC = 3;
constexpr int B = 8, C = 64, T = 32, H = 56, W = 56;

constexpr int ROWS = 8;                      // output rows per block
constexpr int NTHR = 448;                    // 7 dy * 8 chunks * 8 rows
constexpr int NBLK = B * T * (H / ROWS);     // 1792

// LDS layout (floats)
constexpr int X2_STRIDE = 132;               // 8 chunks*16 + 4 pad
constexpr int X2_ROWS   = ROWS + KK - 1;     // 14
constexpr int X2_SIZE   = X2_ROWS * X2_STRIDE;   // 1848
constexpr int X1_STRIDE = 68;                // 8 chunks*8 + 4 pad
constexpr int X1_SIZE   = ROWS * X1_STRIDE;  // 544
constexpr int CBUF      = X2_SIZE + X1_SIZE; // 2392 floats per channel
constexpr int W_SIZE    = C * 56;            // [c][dy*8+j], 3584
constexpr int SMEM_FLOATS = W_SIZE + 4 * CBUF;   // 13152 floats = 52.6 KB

__global__ __launch_bounds__(NTHR)
void corr_fwd(const float* __restrict__ x, const float* __restrict__ fw,
              float* __restrict__ out) {
  __shared__ float smem[SMEM_FLOATS];
  float* w_s = smem;

  const int tid = threadIdx.x;
  const int dy  = tid % 7;
  const int q   = (tid / 7) % 8;
  const int r   = tid / 56;

  int blk = blockIdx.x;
  const int rt = blk % (H / ROWS);
  blk /= (H / ROWS);
  const int t = blk % T;
  const int b = blk / T;
  const int h0 = rt * ROWS;
  const int tp = (t > 0) ? (t - 1) : 0;

  // ---- stage weights * (1/64) for all c, padded to 8 per (c,dy) row ----
  for (int sid = tid; sid < W_SIZE; sid += NTHR) {
    const int c   = sid / 56;
    const int rm  = sid - c * 56;
    const int dyw = rm >> 3;
    const int j   = rm & 7;
    float v = 0.f;
    if (j < 7) v = fw[((c * T + t) * KK + dyw) * KK + j] * (1.0f / 64.0f);
    w_s[sid] = v;
  }
  // ---- zero-init channel buffers once: halo slots rely on staying 0 ----
  for (int i = tid; i < 4 * CBUF; i += NTHR) smem[W_SIZE + i] = 0.f;

  // ---- staging coordinates (hoisted) ----
  int g2[4], l2[4]; bool ok2[4];
#pragma unroll
  for (int k = 0; k < 4; ++k) {
    const int sid = tid + k * NTHR;
    const int rr  = sid >> 7;
    const int qq  = (sid >> 4) & 7;
    const int j   = sid & 15;
    const int hg  = h0 + rr - PADC;
    const int wg  = qq * 7 + j - PADC;
    const bool ok = (hg >= 0) && (hg < H) && (wg >= 0) && (wg < W);
    g2[k] = ok ? (hg * W + wg) : 0;
    ok2[k] = ok;
    l2[k] = rr * X2_STRIDE + qq * 16 + j;
  }
  int g1a, l1a; bool ok1a;
  {
    const int sid = tid;
    const int rr = sid >> 6, qq = (sid >> 3) & 7, j = sid & 7;
    const int wg = qq * 7 + j;
    ok1a = (wg < W);
    g1a = ok1a ? ((h0 + rr) * W + wg) : 0;
    l1a = rr * X1_STRIDE + qq * 8 + j;
  }
  const bool hasB = (tid < 512 - NTHR);
  int g1b = 0, l1b = 0; bool ok1b = false;
  if (hasB) {
    const int sid = tid + NTHR;
    const int rr = sid >> 6, qq = (sid >> 3) & 7, j = sid & 7;
    const int wg = qq * 7 + j;
    ok1b = (wg < W);
    g1b = ok1b ? ((h0 + rr) * W + wg) : 0;
    l1b = rr * X1_STRIDE + qq * 8 + j;
  }

  float acc[7][7];
#pragma unroll
  for (int a = 0; a < 7; ++a)
#pragma unroll
    for (int e = 0; e < 7; ++e) acc[a][e] = 0.f;

  const size_t slice   = (size_t)H * W;        // 3136
  const size_t cstride = (size_t)T * slice;    // 100352
  const float* xb2 = x + ((size_t)(b * C) * T + t)  * slice;
  const float* xb1 = x + ((size_t)(b * C) * T + tp) * slice;

  // rolling global pointers (advance 2 channels per load_set call)
  const float* n2 = xb2;
  const float* n1 = xb1;

  // ---- 3 register staging sets (depth-3 software pipeline) ----
  float S2[3][2][4], S1A[3][2], S1B[3][2];

  auto load_set = [&](auto SC) {
    constexpr int S = decltype(SC)::value;
#pragma unroll
    for (int u = 0; u < 2; ++u) {
      const float* p2 = n2 + (size_t)u * cstride;
      const float* p1 = n1 + (size_t)u * cstride;
#pragma unroll
      for (int k = 0; k < 4; ++k) S2[S][u][k] = p2[g2[k]];
      S1A[S][u] = p1[g1a];
      if (hasB) S1B[S][u] = p1[g1b];
    }
    n2 += 2 * cstride;
    n1 += 2 * cstride;
  };
  auto write_set = [&](auto SC, float* base) {
    constexpr int S = decltype(SC)::value;
#pragma unroll
    for (int u = 0; u < 2; ++u) {
      float* x2s = base + u * CBUF;
      float* x1s = x2s + X2_SIZE;
#pragma unroll
      for (int k = 0; k < 4; ++k)
        if (ok2[k]) x2s[l2[k]] = S2[S][u][k];
      if (ok1a) x1s[l1a] = S1A[S][u];
      if (hasB && ok1b) x1s[l1b] = S1B[S][u];
    }
  };
  auto compute2 = [&](const float* base, int c0) {
#pragma unroll
    for (int u = 0; u < 2; ++u) {
      const float* x2s = base + u * CBUF;
      const float* x1s = x2s + X2_SIZE;
      const float4* zp = reinterpret_cast<const float4*>(x2s + (r + dy) * X2_STRIDE + q * 16);
      const float4 z0 = zp[0], z1 = zp[1], z2v = zp[2], z3v = zp[3];
      const float4* xp = reinterpret_cast<const float4*>(x1s + r * X1_STRIDE + q * 8);
      const float4 xa = xp[0], xbv = xp[1];
      const float4* wp = reinterpret_cast<const float4*>(w_s + (c0 + u) * 56 + dy * 8);
      const float4 wa = wp[0], wbv = wp[1];

      const float zz[16] = {z0.x, z0.y, z0.z, z0.w,  z1.x, z1.y, z1.z, z1.w,
                            z2v.x, z2v.y, z2v.z, z2v.w,  z3v.x, z3v.y, z3v.z, z3v.w};
      const float xx[7]  = {xa.x, xa.y, xa.z, xa.w,  xbv.x, xbv.y, xbv.z};
      const float wv[7]  = {wa.x, wa.y, wa.z, wa.w,  wbv.x, wbv.y, wbv.z};

#pragma unroll
      for (int i = 0; i < 7; ++i)
#pragma unroll
        for (int dx = 0; dx < 7; ++dx)
          acc[dx][i] = fmaf(wv[dx], xx[i] * zz[i + dx], acc[dx][i]);
    }
  };

  float* buf0 = smem + W_SIZE;
  float* buf1 = buf0 + 2 * CBUF;

  // stage s: ds_write set (s%3) [loaded 3 stages ago], re-issue its loads for
  // stage s+3, barrier, compute channels 2s,2s+1 from buf (s%2).
  auto stage = [&](auto SC, float* base, int s, bool doLoad) {
    write_set(SC, base);
    if (doLoad) load_set(SC);
    __syncthreads();
    compute2(base, 2 * s);
  };

  // prologue: channels 0..5 into the 3 sets
  load_set(std::integral_constant<int, 0>{});
  load_set(std::integral_constant<int, 1>{});
  load_set(std::integral_constant<int, 2>{});

  __syncthreads();  // zero-init + weights complete before first ds_writes

  for (int bs = 0; bs < 30; bs += 6) {
    stage(std::integral_constant<int, 0>{}, buf0, bs + 0, (bs + 3) < 32);
    stage(std::integral_constant<int, 1>{}, buf1, bs + 1, (bs + 4) < 32);
    stage(std::integral_constant<int, 2>{}, buf0, bs + 2, (bs + 5) < 32);
    stage(std::integral_constant<int, 0>{}, buf1, bs + 3, (bs + 6) < 32);
    stage(std::integral_constant<int, 1>{}, buf0, bs + 4, (bs + 7) < 32);
    stage(std::integral_constant<int, 2>{}, buf1, bs + 5, (bs + 8) < 32);
  }
  stage(std::integral_constant<int, 0>{}, buf0, 30, false);
  stage(std::integral_constant<int, 1>{}, buf1, 31, false);

  // ---- coalesced write-out via LDS transpose (7 phases, one per dy) ----
  float* obuf = smem;  // alias weight region (3584 >= 3136 floats)
#pragma unroll 1
  for (int ph = 0; ph < 7; ++ph) {
    __syncthreads();
    if (dy == ph) {
#pragma unroll
      for (int dx = 0; dx < 7; ++dx)
#pragma unroll
        for (int i = 0; i < 7; ++i)
          obuf[(dx * ROWS + r) * W + q * 7 + i] = acc[dx][i];
    }
    __syncthreads();
#pragma unroll
    for (int mi = 0; mi < 7; ++mi) {
      const int m   = tid + mi * NTHR;
      const int dxl = m / (ROWS * W);
      const int pos = m - dxl * (ROWS * W);
      const int ch  = ph * 7 + dxl;
      out[((size_t)(b * 49 + ch) * T + t) * slice + (size_t)h0 * W + pos] = obuf[m];
    }
  }
}

}  // namespace

extern "C" void kernel_launch(void* const* d_in, const int* in_sizes, int n_in,
                              void* d_out, int out_size, void* d_ws, size_t ws_size,
                              hipStream_t stream) {
  const float* x  = (const float*)d_in[0];
  const float* fw = (const float*)d_in[1];
  float* out      = (float*)d_out;
  corr_fwd<<<NBLK, NTHR, 0, stream>>>(x, fw, out);
}

// Round 4
// 363.661 us; speedup vs baseline: 4.7288x; 4.7288x over previous
//
#include <hip/hip_runtime.h>
#include <type_traits>

namespace {

constexpr int KK   = 7;
constexpr int PADC = 3;
constexpr int B = 8, C = 64, T = 32, H = 56, W = 56;

constexpr int ROWS = 8;                      // output rows per block
constexpr int NTHR = 448;                    // 7 dy * 8 chunks * 8 rows
constexpr int NBLK = B * T * (H / ROWS);     // 1792

// LDS layout (floats)
constexpr int X2_STRIDE = 132;               // 8 chunks*16 + 4 pad
constexpr int X2_ROWS   = ROWS + KK - 1;     // 14
constexpr int X2_SIZE   = X2_ROWS * X2_STRIDE;   // 1848
constexpr int X1_STRIDE = 68;                // 8 chunks*8 + 4 pad
constexpr int X1_SIZE   = ROWS * X1_STRIDE;  // 544
constexpr int CBUF      = X2_SIZE + X1_SIZE; // 2392 floats per channel
constexpr int W_SIZE    = C * 56;            // [c][dy*8+j], 3584
constexpr int SMEM_FLOATS = W_SIZE + 2 * CBUF;   // 8368 floats = 33.5 KB

__global__ __launch_bounds__(NTHR)
void corr_fwd(const float* __restrict__ x, const float* __restrict__ fw,
              float* __restrict__ out) {
  __shared__ float smem[SMEM_FLOATS];
  float* w_s = smem;

  const int tid = threadIdx.x;
  const int dy  = tid % 7;
  const int q   = (tid / 7) % 8;
  const int r   = tid / 56;

  int blk = blockIdx.x;
  const int rt = blk % (H / ROWS);
  blk /= (H / ROWS);
  const int t = blk % T;
  const int b = blk / T;
  const int h0 = rt * ROWS;
  const int tp = (t > 0) ? (t - 1) : 0;

  // ---- stage weights * (1/64) for all c, padded to 8 per (c,dy) row ----
  for (int sid = tid; sid < W_SIZE; sid += NTHR) {
    const int c   = sid / 56;
    const int rm  = sid - c * 56;
    const int dyw = rm >> 3;
    const int j   = rm & 7;
    float v = 0.f;
    if (j < 7) v = fw[((c * T + t) * KK + dyw) * KK + j] * (1.0f / 64.0f);
    w_s[sid] = v;
  }
  // ---- zero-init channel buffers once: halo slots rely on staying 0 ----
  for (int i = tid; i < 2 * CBUF; i += NTHR) smem[W_SIZE + i] = 0.f;

  // ---- staging coordinates (hoisted) ----
  int g2[4], l2[4]; bool ok2[4];
#pragma unroll
  for (int k = 0; k < 4; ++k) {
    const int sid = tid + k * NTHR;
    const int rr  = sid >> 7;
    const int qq  = (sid >> 4) & 7;
    const int j   = sid & 15;
    const int hg  = h0 + rr - PADC;
    const int wg  = qq * 7 + j - PADC;
    const bool ok = (hg >= 0) && (hg < H) && (wg >= 0) && (wg < W);
    g2[k] = ok ? (hg * W + wg) : 0;
    ok2[k] = ok;
    l2[k] = rr * X2_STRIDE + qq * 16 + j;
  }
  int g1a, l1a; bool ok1a;
  {
    const int sid = tid;
    const int rr = sid >> 6, qq = (sid >> 3) & 7, j = sid & 7;
    const int wg = qq * 7 + j;
    ok1a = (wg < W);
    g1a = ok1a ? ((h0 + rr) * W + wg) : 0;
    l1a = rr * X1_STRIDE + qq * 8 + j;
  }
  const bool hasB = (tid < 512 - NTHR);
  int g1b = 0, l1b = 0; bool ok1b = false;
  if (hasB) {
    const int sid = tid + NTHR;
    const int rr = sid >> 6, qq = (sid >> 3) & 7, j = sid & 7;
    const int wg = qq * 7 + j;
    ok1b = (wg < W);
    g1b = ok1b ? ((h0 + rr) * W + wg) : 0;
    l1b = rr * X1_STRIDE + qq * 8 + j;
  }

  float acc[7][7];
#pragma unroll
  for (int a = 0; a < 7; ++a)
#pragma unroll
    for (int e = 0; e < 7; ++e) acc[a][e] = 0.f;

  const size_t slice   = (size_t)H * W;        // 3136
  const size_t cstride = (size_t)T * slice;    // 100352
  const float* xb2 = x + ((size_t)(b * C) * T + t)  * slice;
  const float* xb1 = x + ((size_t)(b * C) * T + tp) * slice;

  // rolling global pointers (advance 1 channel per load_set call)
  const float* n2 = xb2;
  const float* n1 = xb1;

  // ---- 3 register staging sets, 1 channel each (depth-3 SW pipeline) ----
  float S2[3][4], S1A[3], S1B[3];

  auto load_set = [&](auto SC) {
    constexpr int S = decltype(SC)::value;
#pragma unroll
    for (int k = 0; k < 4; ++k) S2[S][k] = n2[g2[k]];
    S1A[S] = n1[g1a];
    if (hasB) S1B[S] = n1[g1b];
    n2 += cstride;
    n1 += cstride;
  };
  auto write_set = [&](auto SC, float* x2s) {
    constexpr int S = decltype(SC)::value;
    float* x1s = x2s + X2_SIZE;
#pragma unroll
    for (int k = 0; k < 4; ++k)
      if (ok2[k]) x2s[l2[k]] = S2[S][k];
    if (ok1a) x1s[l1a] = S1A[S];
    if (hasB && ok1b) x1s[l1b] = S1B[S];
  };
  auto compute1 = [&](const float* x2s, int c) {
    const float* x1s = x2s + X2_SIZE;
    const float4* zp = reinterpret_cast<const float4*>(x2s + (r + dy) * X2_STRIDE + q * 16);
    const float4 z0 = zp[0], z1 = zp[1], z2v = zp[2], z3v = zp[3];
    const float4* xp = reinterpret_cast<const float4*>(x1s + r * X1_STRIDE + q * 8);
    const float4 xa = xp[0], xbv = xp[1];
    const float4* wp = reinterpret_cast<const float4*>(w_s + c * 56 + dy * 8);
    const float4 wa = wp[0], wbv = wp[1];

    const float zz[16] = {z0.x, z0.y, z0.z, z0.w,  z1.x, z1.y, z1.z, z1.w,
                          z2v.x, z2v.y, z2v.z, z2v.w,  z3v.x, z3v.y, z3v.z, z3v.w};
    const float xx[7]  = {xa.x, xa.y, xa.z, xa.w,  xbv.x, xbv.y, xbv.z};
    const float wv[7]  = {wa.x, wa.y, wa.z, wa.w,  wbv.x, wbv.y, wbv.z};

#pragma unroll
    for (int i = 0; i < 7; ++i)
#pragma unroll
      for (int dx = 0; dx < 7; ++dx)
        acc[dx][i] = fmaf(wv[dx], xx[i] * zz[i + dx], acc[dx][i]);
  };

  float* buf0 = smem + W_SIZE;
  float* buf1 = buf0 + CBUF;

  // stage s (channel c=s): ds_write set (s%3) [loaded 3 stages ago], re-issue
  // its loads for channel s+3, barrier, compute channel s from buf (s%2).
  auto stage = [&](auto SC, float* base, int c, bool doLoad) {
    write_set(SC, base);
    if (doLoad) load_set(SC);
    __syncthreads();
    compute1(base, c);
  };

  // prologue: channels 0,1,2 into the 3 sets
  load_set(std::integral_constant<int, 0>{});
  load_set(std::integral_constant<int, 1>{});
  load_set(std::integral_constant<int, 2>{});

  __syncthreads();  // zero-init + weights complete before first ds_writes

  for (int bs = 0; bs < 60; bs += 6) {
    stage(std::integral_constant<int, 0>{}, buf0, bs + 0, true);
    stage(std::integral_constant<int, 1>{}, buf1, bs + 1, true);
    stage(std::integral_constant<int, 2>{}, buf0, bs + 2, true);
    stage(std::integral_constant<int, 0>{}, buf1, bs + 3, true);
    stage(std::integral_constant<int, 1>{}, buf0, bs + 4, true);
    stage(std::integral_constant<int, 2>{}, buf1, bs + 5, true);
  }
  // tail: channels 60..63 (load only for 60 -> channel 63)
  stage(std::integral_constant<int, 0>{}, buf0, 60, true);
  stage(std::integral_constant<int, 1>{}, buf1, 61, false);
  stage(std::integral_constant<int, 2>{}, buf0, 62, false);
  stage(std::integral_constant<int, 0>{}, buf1, 63, false);

  // ---- coalesced write-out via LDS transpose (7 phases, one per dy) ----
  float* obuf = smem;  // alias weight region (3584 >= 3136 floats)
#pragma unroll 1
  for (int ph = 0; ph < 7; ++ph) {
    __syncthreads();
    if (dy == ph) {
#pragma unroll
      for (int dx = 0; dx < 7; ++dx)
#pragma unroll
        for (int i = 0; i < 7; ++i)
          obuf[(dx * ROWS + r) * W + q * 7 + i] = acc[dx][i];
    }
    __syncthreads();
#pragma unroll
    for (int mi = 0; mi < 7; ++mi) {
      const int m   = tid + mi * NTHR;
      const int dxl = m / (ROWS * W);
      const int pos = m - dxl * (ROWS * W);
      const int ch  = ph * 7 + dxl;
      out[((size_t)(b * 49 + ch) * T + t) * slice + (size_t)h0 * W + pos] = obuf[m];
    }
  }
}

}  // namespace

extern "C" void kernel_launch(void* const* d_in, const int* in_sizes, int n_in,
                              void* d_out, int out_size, void* d_ws, size_t ws_size,
                              hipStream_t stream) {
  const float* x  = (const float*)d_in[0];
  const float* fw = (const float*)d_in[1];
  float* out      = (float*)d_out;
  corr_fwd<<<NBLK, NTHR, 0, stream>>>(x, fw, out);
}